// Round 6
// baseline (4118.079 us; speedup 1.0000x reference)
//
#include <hip/hip_runtime.h>
#include <hip/hip_bf16.h>

// LSTM_Net round 6: batch-group partitioning.
// Invariant ~14us/superstep across r3-r5 despite store & sync overhauls.
// Remaining shared cost: every WG read ALL 64 batch rows of h (96-192KB/step)
// though it computes only a 64x16... -> but the recurrence is INDEPENDENT per
// batch row. Repartition: 4 row-groups (16 rows) x 24 col-WGs x 2 layers:
//   - per-WG h read/step: 24KB (L0) / 48KB (L1), 4x less; aggregate 4x less.
//   - per-group counters: 24 producers/line (was 96), 8 decoupled pipelines.
//   - L1 computes h2@Whh half BEFORE waiting on ctr0 (hides the wait).
//   - full-line sc1 stores: each wave stores 4 complete 64B rows via LDS.
// Coherence model unchanged: rings (first-touch reads), sc1 write-through
// stores, relaxed agent atomics ordered by barrier vmcnt drain. No fences.

#define B_  64
#define T_  256
#define IN_ 64
#define H_  768
#define G_  3072   // 4*H
#define K0_ 832    // IN_ + H_
#define K1_ 1536   // 2*H_
#define NGRP 4
#define NCW  24
#define NWGL 96            // WGs per layer
#define NWG  192
#define SLOT_ (B_ * H_)    // 49152 elements per ring slot

typedef __bf16 bf16_t;
typedef bf16_t bf16x8 __attribute__((ext_vector_type(8)));
typedef float  f32x4  __attribute__((ext_vector_type(4)));

__device__ __forceinline__ unsigned short f2bf(float f) {
    union { float f; unsigned u; } v; v.f = f;
    unsigned r = v.u + 0x7FFFu + ((v.u >> 16) & 1u);
    return (unsigned short)(r >> 16);
}
__device__ __forceinline__ float sigm(float x) {
    return 1.0f / (1.0f + expf(-x));
}
// dword store that bypasses L1/L2 to the agent coherence point.
__device__ __forceinline__ void st_llc_u32(unsigned* p, unsigned v) {
    asm volatile("global_store_dword %0, %1, off sc1" :: "v"(p), "v"(v) : "memory");
}
#define MFMA16(a, b, c) __builtin_amdgcn_mfma_f32_16x16x32_bf16((a), (b), (c), 0, 0, 0)

// ---------------- prep ----------------
__global__ __launch_bounds__(256) void prep_kernel(
    const float* __restrict__ x,
    const float* __restrict__ Wih0, const float* __restrict__ Whh0,
    const float* __restrict__ bih0, const float* __restrict__ bhh0,
    const float* __restrict__ Wih1, const float* __restrict__ Whh1,
    const float* __restrict__ bih1, const float* __restrict__ bhh1,
    unsigned short* __restrict__ xsT,    // [T][B][64]
    unsigned short* __restrict__ W0cat,  // [3072][832]
    unsigned short* __restrict__ W1cat,  // [3072][1536]
    float* __restrict__ bias0, float* __restrict__ bias1,
    int* __restrict__ ctrs)              // [2048] ints
{
    int i = blockIdx.x * blockDim.x + threadIdx.x;
    int stride = gridDim.x * blockDim.x;
    for (int j = i; j < B_ * T_ * IN_; j += stride) {
        int b = j >> 14;
        int t = (j >> 6) & (T_ - 1);
        int k = j & (IN_ - 1);
        xsT[(((size_t)t * B_) + b) * IN_ + k] = f2bf(x[j] * (1.0f / 1.5f));
    }
    for (int j = i; j < G_ * IN_; j += stride) {
        int r = j >> 6; int k = j & 63;
        W0cat[(size_t)r * K0_ + k] = f2bf(Wih0[j]);
    }
    for (int j = i; j < G_ * H_; j += stride) {
        int r = j / H_; int k = j - r * H_;
        W0cat[(size_t)r * K0_ + IN_ + k] = f2bf(Whh0[j]);
        W1cat[(size_t)r * K1_ + k]       = f2bf(Wih1[j]);
        W1cat[(size_t)r * K1_ + H_ + k]  = f2bf(Whh1[j]);
    }
    for (int j = i; j < G_; j += stride) {
        bias0[j] = bih0[j] + bhh0[j];
        bias1[j] = bih1[j] + bhh1[j];
    }
    for (int j = i; j < 2048; j += stride) ctrs[j] = 0;
}

// ---------------- persistent wavefront recurrence ----------------
// h rings: [t][B][H] row-major bf16; group g owns rows g*16..g*16+15.
// ctr0[g] = ctrs[g*64]; ctr1[g] = ctrs[1024 + g*64].
__global__ __launch_bounds__(256) void lstm_persistent(
    const unsigned short* __restrict__ xsT,
    const unsigned short* __restrict__ W0cat,
    const unsigned short* __restrict__ W1cat,
    const float* __restrict__ bias0, const float* __restrict__ bias1,
    unsigned short* __restrict__ h1ring,  // [T][64][768]
    unsigned short* __restrict__ h2ring,  // [T][64][768]
    float* __restrict__ hf32,             // [B][H] fp32 (t = T-1)
    int* __restrict__ ctrs)
{
    __shared__ unsigned short ldsb[16][32];   // WG 16-row x 32-col output patch

    const int tid  = threadIdx.x;
    const int lane = tid & 63;
    const int wave = tid >> 6;
    const int wg   = blockIdx.x;
    const bool isL1 = (wg >= NWGL);
    const int lwg  = isL1 ? (wg - NWGL) : wg;
    const int g    = lwg / NCW;          // row group (16 batch rows)
    const int c    = lwg % NCW;          // col-WG (32 h-cols)
    const int c0w  = c * 32 + wave * 8;  // this wave's 8 h-cols
    const int frow = lane & 15;
    const int q    = lane >> 4;          // quad id 0..3
    const int kof  = q * 8;

    int* ctr0 = &ctrs[g * 64];
    int* ctr1 = &ctrs[1024 + g * 64];

    const unsigned short* Wc = isL1 ? W1cat : W0cat;
    const int Kc = isL1 ? K1_ : K0_;
    // B-tiles (mixed-gate): tile0 rows = gates {i,f} cols c0w..c0w+7,
    //                       tile1 rows = gates {g,o} same cols.
    const int q0 = frow >> 3;
    const int colb = c0w + (frow & 7);
    const unsigned short* Bp0 = Wc + (size_t)(q0 * H_ + colb) * Kc + kof;
    const unsigned short* Bp1 = Wc + (size_t)((2 + q0) * H_ + colb) * Kc + kof;

    const float* bias = isL1 ? bias1 : bias0;
    const bool lowhalf = (lane & 15) < 8;
    const int ecol = c0w + (lane & 7);
    float bi = 0.f, bff = 0.f, bg = 0.f, bo = 0.f;
    if (lowhalf) {
        bi  = bias[0 * H_ + ecol];
        bff = bias[1 * H_ + ecol];
        bg  = bias[2 * H_ + ecol];
        bo  = bias[3 * H_ + ecol];
    }
    float creg[4] = {0.f, 0.f, 0.f, 0.f};

    // A-operand: lane reads row g*16+frow, cols kk*32+kof..+7 (16B).
    const size_t aoff = (size_t)(g * 16 + frow) * H_ + kof;
    // Store phase: wave w stores rows w*4..w*4+3 (full 64B lines).
    const int srow = wave * 4 + (lane >> 4);
    const int sword = lane & 15;
    const size_t stoff = (size_t)(g * 16 + srow) * H_ + c * 32 + sword * 2;
    const int ldsrd = srow * 16 + sword;

    if (!isL1) {
        // ------------- layer 0: superstep s computes t = s ------------------
        for (int s = 0; s < T_; ++s) {
            f32x4 acc0 = {0.f, 0.f, 0.f, 0.f};
            f32x4 acc1 = {0.f, 0.f, 0.f, 0.f};
            {   // xs contribution: independent of sync/h.
                const unsigned short* xsp =
                    xsT + ((size_t)s * B_ + g * 16 + frow) * IN_ + kof;
                #pragma unroll
                for (int ki = 0; ki < 2; ki++) {
                    bf16x8 a  = *(const bf16x8*)(xsp + ki * 32);
                    bf16x8 b0 = *(const bf16x8*)(Bp0 + ki * 32);
                    bf16x8 b1 = *(const bf16x8*)(Bp1 + ki * 32);
                    acc0 = MFMA16(a, b0, acc0);
                    acc1 = MFMA16(a, b1, acc1);
                }
            }
            if (s > 0) {
                if (tid == 0) {
                    while (__hip_atomic_load(ctr0, __ATOMIC_RELAXED,
                                             __HIP_MEMORY_SCOPE_AGENT) < NCW * s)
                        __builtin_amdgcn_s_sleep(1);
                }
                __syncthreads();
                const unsigned short* hr = h1ring + (size_t)(s - 1) * SLOT_ + aoff;
                #pragma unroll
                for (int kj = 0; kj < 24; kj++) {
                    bf16x8 a  = *(const bf16x8*)(hr + kj * 32);
                    bf16x8 b0 = *(const bf16x8*)(Bp0 + (kj + 2) * 32);
                    bf16x8 b1 = *(const bf16x8*)(Bp1 + (kj + 2) * 32);
                    acc0 = MFMA16(a, b0, acc0);
                    acc1 = MFMA16(a, b1, acc1);
                }
            }
            f32x4 pacc0, pacc1;
            #pragma unroll
            for (int j = 0; j < 4; j++) {
                pacc0[j] = __shfl_xor(acc0[j], 8);
                pacc1[j] = __shfl_xor(acc1[j], 8);
            }
            if (lowhalf) {
                #pragma unroll
                for (int j = 0; j < 4; j++) {
                    float pi = acc0[j]  + bi;
                    float pf = pacc0[j] + bff;
                    float pg = acc1[j]  + bg;
                    float po = pacc1[j] + bo;
                    float cn = sigm(pf) * creg[j] + sigm(pi) * tanhf(pg);
                    float hn = sigm(po) * tanhf(cn);
                    creg[j] = cn;
                    ldsb[q * 4 + j][wave * 8 + (lane & 7)] = f2bf(hn);
                }
            }
            __syncthreads();   // LDS patch complete across waves
            {
                unsigned v = ((const unsigned*)&ldsb[0][0])[ldsrd];
                st_llc_u32((unsigned*)(h1ring + (size_t)s * SLOT_ + stoff), v);
            }
            __syncthreads();   // vmcnt(0) drain: stores at coherence point
            if (tid == 0) atomicAdd(ctr0, 1);
        }
    } else {
        // ------------- layer 1: superstep s computes t = s - 1 --------------
        for (int s = 1; s <= T_; ++s) {
            const int t = s - 1;
            f32x4 acc0 = {0.f, 0.f, 0.f, 0.f};
            f32x4 acc1 = {0.f, 0.f, 0.f, 0.f};
            // h2@Whh half first: deps usually already published.
            if (t > 0) {
                if (tid == 0) {
                    while (__hip_atomic_load(ctr1, __ATOMIC_RELAXED,
                                             __HIP_MEMORY_SCOPE_AGENT) < NCW * t)
                        __builtin_amdgcn_s_sleep(1);
                }
                __syncthreads();
                const unsigned short* h2r = h2ring + (size_t)(t - 1) * SLOT_ + aoff;
                #pragma unroll
                for (int ki = 0; ki < 24; ki++) {
                    bf16x8 a  = *(const bf16x8*)(h2r + ki * 32);
                    bf16x8 b0 = *(const bf16x8*)(Bp0 + (ki + 24) * 32);
                    bf16x8 b1 = *(const bf16x8*)(Bp1 + (ki + 24) * 32);
                    acc0 = MFMA16(a, b0, acc0);
                    acc1 = MFMA16(a, b1, acc1);
                }
            }
            // h1@Wih half: wait for L0 of step t.
            if (tid == 0) {
                while (__hip_atomic_load(ctr0, __ATOMIC_RELAXED,
                                         __HIP_MEMORY_SCOPE_AGENT) < NCW * s)
                    __builtin_amdgcn_s_sleep(1);
            }
            __syncthreads();
            {
                const unsigned short* h1r = h1ring + (size_t)t * SLOT_ + aoff;
                #pragma unroll
                for (int ki = 0; ki < 24; ki++) {
                    bf16x8 a  = *(const bf16x8*)(h1r + ki * 32);
                    bf16x8 b0 = *(const bf16x8*)(Bp0 + ki * 32);
                    bf16x8 b1 = *(const bf16x8*)(Bp1 + ki * 32);
                    acc0 = MFMA16(a, b0, acc0);
                    acc1 = MFMA16(a, b1, acc1);
                }
            }
            f32x4 pacc0, pacc1;
            #pragma unroll
            for (int j = 0; j < 4; j++) {
                pacc0[j] = __shfl_xor(acc0[j], 8);
                pacc1[j] = __shfl_xor(acc1[j], 8);
            }
            if (lowhalf) {
                #pragma unroll
                for (int j = 0; j < 4; j++) {
                    float pi = acc0[j]  + bi;
                    float pf = pacc0[j] + bff;
                    float pg = acc1[j]  + bg;
                    float po = pacc1[j] + bo;
                    float cn = sigm(pf) * creg[j] + sigm(pi) * tanhf(pg);
                    float hn = sigm(po) * tanhf(cn);
                    creg[j] = cn;
                    ldsb[q * 4 + j][wave * 8 + (lane & 7)] = f2bf(hn);
                    if (t == T_ - 1)
                        hf32[(size_t)(g * 16 + q * 4 + j) * H_ + ecol] = hn;
                }
            }
            __syncthreads();
            {
                unsigned v = ((const unsigned*)&ldsb[0][0])[ldsrd];
                st_llc_u32((unsigned*)(h2ring + (size_t)t * SLOT_ + stoff), v);
            }
            __syncthreads();
            if (tid == 0) atomicAdd(ctr1, 1);
        }
    }
}

// ---------------- head ----------------
__global__ __launch_bounds__(256) void head_kernel(
    const float* __restrict__ hlast,
    const float* __restrict__ W1, const float* __restrict__ b1,
    const float* __restrict__ W2, const float* __restrict__ b2,
    float* __restrict__ out)
{
    __shared__ float hs[H_];
    __shared__ float partial[4];
    int b = blockIdx.x;
    int tid = threadIdx.x;
    for (int j = tid; j < H_; j += 256) hs[j] = hlast[(size_t)b * H_ + j];
    __syncthreads();
    float z = 0.f;
    const float* w = W1 + (size_t)tid * H_;
    for (int j = 0; j < H_; j++) z += hs[j] * w[j];
    z += b1[tid];
    z = z / (1.0f + fabsf(z));
    float p = z * W2[tid];
    #pragma unroll
    for (int off = 32; off > 0; off >>= 1) p += __shfl_down(p, off, 64);
    if ((tid & 63) == 0) partial[tid >> 6] = p;
    __syncthreads();
    if (tid == 0) {
        float s = partial[0] + partial[1] + partial[2] + partial[3];
        out[b] = (s + b2[0]) * 70.0f;
    }
}

extern "C" void kernel_launch(void* const* d_in, const int* in_sizes, int n_in,
                              void* d_out, int out_size, void* d_ws, size_t ws_size,
                              hipStream_t stream) {
    const float* x    = (const float*)d_in[0];
    const float* Wih0 = (const float*)d_in[1];
    const float* Whh0 = (const float*)d_in[2];
    const float* bih0 = (const float*)d_in[3];
    const float* bhh0 = (const float*)d_in[4];
    const float* Wih1 = (const float*)d_in[5];
    const float* Whh1 = (const float*)d_in[6];
    const float* bih1 = (const float*)d_in[7];
    const float* bhh1 = (const float*)d_in[8];
    const float* W1   = (const float*)d_in[9];
    const float* b1   = (const float*)d_in[10];
    const float* W2   = (const float*)d_in[11];
    const float* b2   = (const float*)d_in[12];
    float* out = (float*)d_out;

    char* w = (char*)d_ws;
    int* ctrs = (int*)w;                          w += 8192;
    unsigned short* h1ring = (unsigned short*)w;  w += (size_t)T_ * SLOT_ * 2;
    unsigned short* h2ring = (unsigned short*)w;  w += (size_t)T_ * SLOT_ * 2;
    unsigned short* xsT    = (unsigned short*)w;  w += (size_t)B_ * T_ * IN_ * 2;
    unsigned short* W0cat  = (unsigned short*)w;  w += (size_t)G_ * K0_ * 2;
    unsigned short* W1cat  = (unsigned short*)w;  w += (size_t)G_ * K1_ * 2;
    float* bias0 = (float*)w;                     w += G_ * 4;
    float* bias1 = (float*)w;                     w += G_ * 4;
    float* hf32  = (float*)w;                     w += (size_t)B_ * H_ * 4;

    prep_kernel<<<1024, 256, 0, stream>>>(x, Wih0, Whh0, bih0, bhh0,
                                          Wih1, Whh1, bih1, bhh1,
                                          xsT, W0cat, W1cat, bias0, bias1, ctrs);
    lstm_persistent<<<NWG, 256, 0, stream>>>(xsT, W0cat, W1cat, bias0, bias1,
                                             h1ring, h2ring, hf32, ctrs);
    head_kernel<<<B_, 256, 0, stream>>>(hf32, W1, b1, W2, b2, out);
}

// Round 7
// 3860.595 us; speedup vs baseline: 1.0667x; 1.0667x over previous
//
#include <hip/hip_runtime.h>
#include <hip/hip_bf16.h>

// LSTM_Net round 7: r5 structure + RMW-free sync.
// r6 post-mortem: row-major ring broke coalescing (4x fetch amplification,
// FETCH unchanged) + extra barrier -> regression. Reverted to r5 layout.
// r3-r6 eliminated: fences, store scatter, poll congestion, data volume.
// Remaining suspect: publish fan-in = 96 same-line atomicAdd RMWs per layer
// per step, serialized at the MALL ALU (~3-10us until ctr reaches 96*s).
// This round (single variable vs r5): per-WG flag STORES (no RMW, 6 lines,
// parallel) + consumer wave-scan poll (2 vector loads + __all, per poll).
//   flags0[wg] = L0 WG's completed-superstep count (stores s+1 after step s)
//   flags1[wg] = L1 WG's completed-superstep count (stores s after step s)
//   L0 step s waits all flags0 >= s; L1 step s waits flags0 >= s && flags1 >= s-1.
// Coherence: rings (first-touch reads), sc1 write-through stores ordered
// before flag store by __syncthreads vmcnt drain, sc1 flag loads. No fences.

#define B_  64
#define T_  256
#define IN_ 64
#define H_  768
#define G_  3072   // 4*H
#define K0_ 832    // IN_ + H_
#define K1_ 1536   // 2*H_
#define NWG0 96
#define NWG  192
#define CB_  96            // col blocks per layer (H/8)
#define SLOT_ (CB_ * 64 * 8)   // elements per ring slot = 49152

typedef __bf16 bf16_t;
typedef bf16_t bf16x8 __attribute__((ext_vector_type(8)));
typedef float  f32x4  __attribute__((ext_vector_type(4)));

__device__ __forceinline__ unsigned short f2bf(float f) {
    union { float f; unsigned u; } v; v.f = f;
    unsigned r = v.u + 0x7FFFu + ((v.u >> 16) & 1u);
    return (unsigned short)(r >> 16);
}
__device__ __forceinline__ float sigm(float x) {
    return 1.0f / (1.0f + expf(-x));
}
// dword store that bypasses L1/L2 to the agent coherence point.
__device__ __forceinline__ void st_llc_u32(unsigned* p, unsigned v) {
    asm volatile("global_store_dword %0, %1, off sc1" :: "v"(p), "v"(v) : "memory");
}
#define MFMA16(a, b, c) __builtin_amdgcn_mfma_f32_16x16x32_bf16((a), (b), (c), 0, 0, 0)

// ---------------- prep ----------------
__global__ __launch_bounds__(256) void prep_kernel(
    const float* __restrict__ x,
    const float* __restrict__ Wih0, const float* __restrict__ Whh0,
    const float* __restrict__ bih0, const float* __restrict__ bhh0,
    const float* __restrict__ Wih1, const float* __restrict__ Whh1,
    const float* __restrict__ bih1, const float* __restrict__ bhh1,
    unsigned short* __restrict__ xsT,    // [T][B][64]
    unsigned short* __restrict__ W0cat,  // [3072][832]
    unsigned short* __restrict__ W1cat,  // [3072][1536]
    float* __restrict__ bias0, float* __restrict__ bias1,
    int* __restrict__ flags)             // [256]: [0..127] L0, [128..255] L1
{
    int i = blockIdx.x * blockDim.x + threadIdx.x;
    int stride = gridDim.x * blockDim.x;
    for (int j = i; j < B_ * T_ * IN_; j += stride) {
        int b = j >> 14;
        int t = (j >> 6) & (T_ - 1);
        int k = j & (IN_ - 1);
        xsT[(((size_t)t * B_) + b) * IN_ + k] = f2bf(x[j] * (1.0f / 1.5f));
    }
    for (int j = i; j < G_ * IN_; j += stride) {
        int r = j >> 6; int k = j & 63;
        W0cat[(size_t)r * K0_ + k] = f2bf(Wih0[j]);
    }
    for (int j = i; j < G_ * H_; j += stride) {
        int r = j / H_; int k = j - r * H_;
        W0cat[(size_t)r * K0_ + IN_ + k] = f2bf(Whh0[j]);
        W1cat[(size_t)r * K1_ + k]       = f2bf(Wih1[j]);
        W1cat[(size_t)r * K1_ + H_ + k]  = f2bf(Whh1[j]);
    }
    for (int j = i; j < G_; j += stride) {
        bias0[j] = bih0[j] + bhh0[j];
        bias1[j] = bih1[j] + bhh1[j];
    }
    // real flag slots (index%128 < 96) start at 0; padding slots at INT_MAX
    // so the lane-parallel scan's padding lanes are always satisfied.
    for (int j = i; j < 256; j += stride)
        flags[j] = ((j & 127) < NWG0) ? 0 : 0x7FFFFFFF;
}

// ---------------- persistent wavefront recurrence ----------------
// h rings: [t][cb][row][8] bf16; cb = col-block (8 cols), one per WG.
__global__ __launch_bounds__(256) void lstm_persistent(
    const unsigned short* __restrict__ xsT,
    const unsigned short* __restrict__ W0cat,
    const unsigned short* __restrict__ W1cat,
    const float* __restrict__ bias0, const float* __restrict__ bias1,
    unsigned short* __restrict__ h1ring,  // [T][96][64][8]
    unsigned short* __restrict__ h2ring,  // [T][96][64][8]
    float* __restrict__ hf32,             // [B][H] fp32 (t = T-1)
    int* __restrict__ flags)              // [256]
{
    __shared__ unsigned short ldsb[4][16][8];   // per-wave 16x8 output patch

    const int tid  = threadIdx.x;
    const int lane = tid & 63;
    const int wave = tid >> 6;
    const int wg   = blockIdx.x;
    const bool isL1 = (wg >= NWG0);
    const int cb   = isL1 ? (wg - NWG0) : wg;
    const int c0   = cb * 8;
    const int frow = lane & 15;
    const int q    = lane >> 4;       // quad id 0..3
    const int kof  = q * 8;
    const int m0   = wave * 16;

    int* flags0 = &flags[0];
    int* flags1 = &flags[128];
    const int pi1 = lane;               // poll index 1 (0..63)
    const int pi2 = 64 + (lane & 31);   // poll index 2 (64..95 real, 96..127 pad)

    const unsigned short* Wc = isL1 ? W1cat : W0cat;
    const int Kc = isL1 ? K1_ : K0_;
    int q0 = frow >> 3,        col0 = c0 + (frow & 7);   // B-tile0: gates i,f
    const unsigned short* Bp0 = Wc + (size_t)(q0 * H_ + col0) * Kc + kof;
    const unsigned short* Bp1 = Wc + (size_t)((2 + q0) * H_ + col0) * Kc + kof;

    const float* bias = isL1 ? bias1 : bias0;
    const bool lowhalf = (lane & 15) < 8;
    const int ecol = c0 + (lane & 7);
    float bi = 0.f, bff = 0.f, bg = 0.f, bo = 0.f;
    if (lowhalf) {
        bi  = bias[0 * H_ + ecol];
        bff = bias[1 * H_ + ecol];
        bg  = bias[2 * H_ + ecol];
        bo  = bias[3 * H_ + ecol];
    }
    float creg[4] = {0.f, 0.f, 0.f, 0.f};

    // A-operand offset within a ring slot: quad q reads cb-index (kj*4+q),
    // row m0+frow, 8 contiguous cols (16B/lane, packed per quad).
    const size_t aoff = (size_t)q * 512 + (size_t)(m0 + frow) * 8;
    // Store: wave writes 256B at slot + cb*512 + wave's rows (1KB/WG).
    const size_t stoff_e = (size_t)cb * 512 + (size_t)(m0 + (lane >> 2)) * 8
                         + (size_t)(lane & 3) * 2;   // elements

    if (!isL1) {
        // ------------- layer 0: superstep s computes t = s ------------------
        for (int s = 0; s < T_; ++s) {
            // xs contribution first: independent of sync/h.
            f32x4 acc0 = {0.f, 0.f, 0.f, 0.f};
            f32x4 acc1 = {0.f, 0.f, 0.f, 0.f};
            {
                const unsigned short* xsp =
                    xsT + ((size_t)s * B_ + m0 + frow) * IN_ + kof;
                #pragma unroll
                for (int ki = 0; ki < 2; ki++) {
                    bf16x8 a  = *(const bf16x8*)(xsp + ki * 32);
                    bf16x8 b0 = *(const bf16x8*)(Bp0 + ki * 32);
                    bf16x8 b1 = *(const bf16x8*)(Bp1 + ki * 32);
                    acc0 = MFMA16(a, b0, acc0);
                    acc1 = MFMA16(a, b1, acc1);
                }
            }
            if (s > 0) {
                if (wave == 0) {   // wave-scan poll: all flags0 >= s
                    for (;;) {
                        int fa = __hip_atomic_load(&flags0[pi1], __ATOMIC_RELAXED,
                                                   __HIP_MEMORY_SCOPE_AGENT);
                        int fb = __hip_atomic_load(&flags0[pi2], __ATOMIC_RELAXED,
                                                   __HIP_MEMORY_SCOPE_AGENT);
                        if (__all(fa >= s && fb >= s)) break;
                        __builtin_amdgcn_s_sleep(1);
                    }
                }
                __syncthreads();
                const unsigned short* hr = h1ring + (size_t)(s - 1) * SLOT_ + aoff;
                #pragma unroll
                for (int kj = 0; kj < 24; kj++) {
                    bf16x8 a  = *(const bf16x8*)(hr + kj * 2048);
                    bf16x8 b0 = *(const bf16x8*)(Bp0 + (kj + 2) * 32);
                    bf16x8 b1 = *(const bf16x8*)(Bp1 + (kj + 2) * 32);
                    acc0 = MFMA16(a, b0, acc0);
                    acc1 = MFMA16(a, b1, acc1);
                }
            }
            f32x4 pacc0, pacc1;
            #pragma unroll
            for (int j = 0; j < 4; j++) {
                pacc0[j] = __shfl_xor(acc0[j], 8);
                pacc1[j] = __shfl_xor(acc1[j], 8);
            }
            if (lowhalf) {
                #pragma unroll
                for (int j = 0; j < 4; j++) {
                    float pi = acc0[j]  + bi;
                    float pf = pacc0[j] + bff;
                    float pg = acc1[j]  + bg;
                    float po = pacc1[j] + bo;
                    float cn = sigm(pf) * creg[j] + sigm(pi) * tanhf(pg);
                    float hn = sigm(po) * tanhf(cn);
                    creg[j] = cn;
                    ldsb[wave][q * 4 + j][lane & 7] = f2bf(hn);
                }
            }
            // wave-internal DS ordering: read below sees this wave's writes.
            unsigned v = ((const unsigned*)&ldsb[wave][0][0])[lane];
            st_llc_u32((unsigned*)(h1ring + (size_t)s * SLOT_ + stoff_e), v);
            __syncthreads();   // vmcnt(0) drain: h stores at coherence point
            if (tid == 0) st_llc_u32((unsigned*)&flags0[cb], (unsigned)(s + 1));
        }
    } else {
        // ------------- layer 1: superstep s computes t = s - 1 --------------
        for (int s = 1; s <= T_; ++s) {
            const int t = s - 1;
            if (wave == 0) {   // all flags0 >= s  AND  all flags1 >= s-1
                for (;;) {
                    int fa = __hip_atomic_load(&flags0[pi1], __ATOMIC_RELAXED,
                                               __HIP_MEMORY_SCOPE_AGENT);
                    int fb = __hip_atomic_load(&flags0[pi2], __ATOMIC_RELAXED,
                                               __HIP_MEMORY_SCOPE_AGENT);
                    int ga = __hip_atomic_load(&flags1[pi1], __ATOMIC_RELAXED,
                                               __HIP_MEMORY_SCOPE_AGENT);
                    int gb = __hip_atomic_load(&flags1[pi2], __ATOMIC_RELAXED,
                                               __HIP_MEMORY_SCOPE_AGENT);
                    if (__all(fa >= s && fb >= s && ga >= s - 1 && gb >= s - 1))
                        break;
                    __builtin_amdgcn_s_sleep(1);
                }
            }
            __syncthreads();
            f32x4 acc0 = {0.f, 0.f, 0.f, 0.f};
            f32x4 acc1 = {0.f, 0.f, 0.f, 0.f};
            const unsigned short* h1r = h1ring + (size_t)t * SLOT_ + aoff;
            #pragma unroll
            for (int ki = 0; ki < 24; ki++) {
                bf16x8 a  = *(const bf16x8*)(h1r + ki * 2048);
                bf16x8 b0 = *(const bf16x8*)(Bp0 + ki * 32);
                bf16x8 b1 = *(const bf16x8*)(Bp1 + ki * 32);
                acc0 = MFMA16(a, b0, acc0);
                acc1 = MFMA16(a, b1, acc1);
            }
            if (t > 0) {
                const unsigned short* h2r = h2ring + (size_t)(t - 1) * SLOT_ + aoff;
                #pragma unroll
                for (int ki = 0; ki < 24; ki++) {
                    bf16x8 a  = *(const bf16x8*)(h2r + ki * 2048);
                    bf16x8 b0 = *(const bf16x8*)(Bp0 + (ki + 24) * 32);
                    bf16x8 b1 = *(const bf16x8*)(Bp1 + (ki + 24) * 32);
                    acc0 = MFMA16(a, b0, acc0);
                    acc1 = MFMA16(a, b1, acc1);
                }
            }
            f32x4 pacc0, pacc1;
            #pragma unroll
            for (int j = 0; j < 4; j++) {
                pacc0[j] = __shfl_xor(acc0[j], 8);
                pacc1[j] = __shfl_xor(acc1[j], 8);
            }
            if (lowhalf) {
                #pragma unroll
                for (int j = 0; j < 4; j++) {
                    int row = m0 + q * 4 + j;
                    float pi = acc0[j]  + bi;
                    float pf = pacc0[j] + bff;
                    float pg = acc1[j]  + bg;
                    float po = pacc1[j] + bo;
                    float cn = sigm(pf) * creg[j] + sigm(pi) * tanhf(pg);
                    float hn = sigm(po) * tanhf(cn);
                    creg[j] = cn;
                    ldsb[wave][q * 4 + j][lane & 7] = f2bf(hn);
                    if (t == T_ - 1) hf32[(size_t)row * H_ + ecol] = hn;
                }
            }
            unsigned v = ((const unsigned*)&ldsb[wave][0][0])[lane];
            st_llc_u32((unsigned*)(h2ring + (size_t)t * SLOT_ + stoff_e), v);
            __syncthreads();
            if (tid == 0) st_llc_u32((unsigned*)&flags1[cb], (unsigned)s);
        }
    }
}

// ---------------- head ----------------
__global__ __launch_bounds__(256) void head_kernel(
    const float* __restrict__ hlast,
    const float* __restrict__ W1, const float* __restrict__ b1,
    const float* __restrict__ W2, const float* __restrict__ b2,
    float* __restrict__ out)
{
    __shared__ float hs[H_];
    __shared__ float partial[4];
    int b = blockIdx.x;
    int tid = threadIdx.x;
    for (int j = tid; j < H_; j += 256) hs[j] = hlast[(size_t)b * H_ + j];
    __syncthreads();
    float z = 0.f;
    const float* w = W1 + (size_t)tid * H_;
    for (int j = 0; j < H_; j++) z += hs[j] * w[j];
    z += b1[tid];
    z = z / (1.0f + fabsf(z));
    float p = z * W2[tid];
    #pragma unroll
    for (int off = 32; off > 0; off >>= 1) p += __shfl_down(p, off, 64);
    if ((tid & 63) == 0) partial[tid >> 6] = p;
    __syncthreads();
    if (tid == 0) {
        float s = partial[0] + partial[1] + partial[2] + partial[3];
        out[b] = (s + b2[0]) * 70.0f;
    }
}

extern "C" void kernel_launch(void* const* d_in, const int* in_sizes, int n_in,
                              void* d_out, int out_size, void* d_ws, size_t ws_size,
                              hipStream_t stream) {
    const float* x    = (const float*)d_in[0];
    const float* Wih0 = (const float*)d_in[1];
    const float* Whh0 = (const float*)d_in[2];
    const float* bih0 = (const float*)d_in[3];
    const float* bhh0 = (const float*)d_in[4];
    const float* Wih1 = (const float*)d_in[5];
    const float* Whh1 = (const float*)d_in[6];
    const float* bih1 = (const float*)d_in[7];
    const float* bhh1 = (const float*)d_in[8];
    const float* W1   = (const float*)d_in[9];
    const float* b1   = (const float*)d_in[10];
    const float* W2   = (const float*)d_in[11];
    const float* b2   = (const float*)d_in[12];
    float* out = (float*)d_out;

    char* w = (char*)d_ws;
    int* flags = (int*)w;                         w += 2048;
    unsigned short* h1ring = (unsigned short*)w;  w += (size_t)T_ * SLOT_ * 2;
    unsigned short* h2ring = (unsigned short*)w;  w += (size_t)T_ * SLOT_ * 2;
    unsigned short* xsT    = (unsigned short*)w;  w += (size_t)B_ * T_ * IN_ * 2;
    unsigned short* W0cat  = (unsigned short*)w;  w += (size_t)G_ * K0_ * 2;
    unsigned short* W1cat  = (unsigned short*)w;  w += (size_t)G_ * K1_ * 2;
    float* bias0 = (float*)w;                     w += G_ * 4;
    float* bias1 = (float*)w;                     w += G_ * 4;
    float* hf32  = (float*)w;                     w += (size_t)B_ * H_ * 4;

    prep_kernel<<<1024, 256, 0, stream>>>(x, Wih0, Whh0, bih0, bhh0,
                                          Wih1, Whh1, bih1, bhh1,
                                          xsT, W0cat, W1cat, bias0, bias1, flags);
    lstm_persistent<<<NWG, 256, 0, stream>>>(xsT, W0cat, W1cat, bias0, bias1,
                                             h1ring, h2ring, hf32, flags);
    head_kernel<<<B_, 256, 0, stream>>>(hf32, W1, b1, W2, b2, out);
}